// Round 6
// baseline (26.832 us; speedup 1.0000x reference)
//
#include <hip/hip_runtime.h>

// Problem constants (B=1024, I=128, H=512, O=16)
#define B_DIM 1024
#define I_DIM 128
#define H_DIM 512
#define O_CNT 16
#define NCH 16     // h-chunks per option
#define CH 32      // h rows per chunk (NCH*CH == H_DIM)

// Full 64-lane butterfly reduction (wave = 64 on CDNA4).
__device__ __forceinline__ float wave_reduce_sum(float v) {
#pragma unroll
    for (int off = 32; off > 0; off >>= 1)
        v += __shfl_xor(v, off, 64);
    return v;
}

// Single fused kernel. Block (o,c) with o = bid&15 (keeps all 16 chunks of an
// option on one XCD under round-robin bid->XCD mapping), c = bid>>4.
//   u_s[r]  = dot(W2[o, c*CH+r, :], W3[o, :])     r in [0,32)  (64 KB W2 slice)
//   y_s[i]  = sum_r W1[o, i, c*CH+r] * u_s[r]     i in [0,128) (16 KB W1 slice)
//   for b with opt[b]==o: atomicAdd(out[b], dot(state[b,:], y_s))
// All streaming loads are issued up-front into registers (max MLP); the whole
// 84 KB/block is in flight before any compute.
__global__ __launch_bounds__(512) void k_mega(const float* __restrict__ W1,
                                              const float* __restrict__ W2,
                                              const float* __restrict__ W3,
                                              const float* __restrict__ state,
                                              const int* __restrict__ option,
                                              float* __restrict__ out)
{
    const int o    = blockIdx.x & 15;    // option  (fixes XCD = o%8)
    const int c    = blockIdx.x >> 4;    // chunk [0,16)
    const int tid  = threadIdx.x;        // [0,512)
    const int w    = tid >> 6;           // wave [0,8)
    const int lane = tid & 63;
    const int h0   = c * CH;

    __shared__ float u_s[CH];
    __shared__ float y_s[I_DIM];
    __shared__ int   opt_s[B_DIM];

    // ---- Issue ALL streaming loads up-front ----
    // option[] staging (2 coalesced ints per thread).
    opt_s[tid]       = option[tid];
    opt_s[tid + 512] = option[tid + 512];

    // W3 fragment (broadcast 2 KB).
    const float4* w3p = (const float4*)(W3 + (size_t)o * H_DIM);
    const float4 c0 = w3p[lane], c1 = w3p[lane + 64];

    // W2: wave w owns chunk-rows 4w..4w+3; 2 float4 per row per lane (32 VGPR).
    const float4* w2b = (const float4*)(W2 + ((size_t)o * H_DIM + h0 + 4 * w) * H_DIM);
    float4 a[4][2];
#pragma unroll
    for (int j = 0; j < 4; ++j) {
        a[j][0] = w2b[(size_t)j * (H_DIM / 4) + lane];
        a[j][1] = w2b[(size_t)j * (H_DIM / 4) + lane + 64];
    }

    // W1: threads 0..127 each own one 128 B line-aligned row-slice (32 VGPR).
    float4 w1r[8];
    if (tid < I_DIM) {
        const float4* wp = (const float4*)(W1 + ((size_t)o * I_DIM + tid) * H_DIM + h0);
#pragma unroll
        for (int q = 0; q < 8; ++q) w1r[q] = wp[q];
    }

    // ---- Phase A: u-chunk (4 row-dots per wave). ----
#pragma unroll
    for (int j = 0; j < 4; ++j) {
        float acc = a[j][0].x*c0.x + a[j][0].y*c0.y + a[j][0].z*c0.z + a[j][0].w*c0.w
                  + a[j][1].x*c1.x + a[j][1].y*c1.y + a[j][1].z*c1.z + a[j][1].w*c1.w;
        acc = wave_reduce_sum(acc);
        if (lane == 0) u_s[w * 4 + j] = acc;
    }
    __syncthreads();

    // ---- Phase B: y-chunk (u_s reads are all-lane broadcasts). ----
    if (tid < I_DIM) {
        float yv = 0.f;
#pragma unroll
        for (int q = 0; q < 8; ++q)
            yv += w1r[q].x * u_s[4*q+0] + w1r[q].y * u_s[4*q+1]
                + w1r[q].z * u_s[4*q+2] + w1r[q].w * u_s[4*q+3];
        y_s[tid] = yv;
    }
    __syncthreads();

    // ---- Phase C: partial outputs. Wave w scans samples [w*128,(w+1)*128). ----
    const float2 yv2 = *(const float2*)(y_s + 2 * lane);   // 2-way LDS = free
#pragma unroll
    for (int g = 0; g < 2; ++g) {
        const int bbase = w * 128 + g * 64;
        unsigned long long mask = __ballot(opt_s[bbase + lane] == o);
        while (mask) {
            const int bit = __ffsll((long long)mask) - 1;
            mask &= mask - 1;
            const int b = bbase + bit;
            const float2 s = ((const float2*)(state + (size_t)b * I_DIM))[lane];
            float acc = s.x * yv2.x + s.y * yv2.y;
            acc = wave_reduce_sum(acc);
            if (lane == 0) atomicAdd(out + b, acc);   // device-scope, ~16 adds/sample total
        }
    }
}

extern "C" void kernel_launch(void* const* d_in, const int* in_sizes, int n_in,
                              void* d_out, int out_size, void* d_ws, size_t ws_size,
                              hipStream_t stream) {
    const float* state  = (const float*)d_in[0];
    // d_in[1] = action, unused by the reference forward.
    const float* W1     = (const float*)d_in[2];
    const float* W2     = (const float*)d_in[3];
    const float* W3     = (const float*)d_in[4];
    const int*   option = (const int*)d_in[5];
    float* out = (float*)d_out;

    // out accumulates via atomics -> must start at zero every call.
    hipMemsetAsync(out, 0, (size_t)out_size * sizeof(float), stream);

    // 256 blocks x 512 threads: 1 block/CU, each streaming a disjoint
    // 64 KB W2 + 16 KB W1 slice at full aggregate HBM BW.
    k_mega<<<O_CNT * NCH, 512, 0, stream>>>(W1, W2, W3, state, option, out);
}